// Round 14
// baseline (166.587 us; speedup 1.0000x reference)
//
#include <hip/hip_runtime.h>
#include <hip/hip_bf16.h>

#define T_LOCAL 2048
#define S_GLOBAL 4096
#define NQ 16
#define NK 8
#define HN 128

// 128^-0.5 * log2(e)
#define SCALE2 0.12753102541996022f

typedef __attribute__((ext_vector_type(8))) short short8;
typedef __attribute__((ext_vector_type(4))) float f32x4;

static __device__ __forceinline__ ushort f2bf(float x) {
  unsigned u = __builtin_bit_cast(unsigned, x);
  unsigned r = (u + 0x7fffu + ((u >> 16) & 1u)) >> 16;
  return (ushort)r;
}

static __device__ __forceinline__ void gload16(const ushort* g, ushort* lds) {
  __builtin_amdgcn_global_load_lds(
      (const __attribute__((address_space(1))) void*)g,
      (__attribute__((address_space(3))) void*)lds, 16, 0, 0);
}

// ---- pre-pass 1: K f32 -> bf16 (same layout [S][NK][HN]) ----
__global__ void k_convert(const float* __restrict__ K, ushort* __restrict__ Kb) {
  size_t i = ((size_t)blockIdx.x * 256 + threadIdx.x) * 4;
  float4 v = *(const float4*)(K + i);
  ushort4 o;
  o.x = f2bf(v.x); o.y = f2bf(v.y); o.z = f2bf(v.z); o.w = f2bf(v.w);
  *(ushort4*)(Kb + i) = o;
}

// ---- pre-pass 2: V f32 [S][NK][HN] -> Vt bf16 [NK][HN][S] (per-head transpose) ----
__global__ void v_transpose(const float* __restrict__ V, ushort* __restrict__ Vt) {
  int bid = blockIdx.x;            // 8 heads * 2 d-tiles * 64 p-tiles = 1024
  int h  = bid >> 7;
  int r  = bid & 127;
  int d0 = (r >> 6) << 6;          // 0 or 64
  int p0 = (r & 63) << 6;          // 0..4032
  __shared__ ushort tile[64][72];  // [d_local][p_local], padded
  int tx = threadIdx.x & 15, ty = threadIdx.x >> 4;
  #pragma unroll
  for (int it = 0; it < 4; ++it) {
    int p = p0 + it * 16 + ty;
    int d = tx * 4;
    float4 v = *(const float4*)(V + ((size_t)p * NK + h) * HN + d0 + d);
    tile[d + 0][it * 16 + ty] = f2bf(v.x);
    tile[d + 1][it * 16 + ty] = f2bf(v.y);
    tile[d + 2][it * 16 + ty] = f2bf(v.z);
    tile[d + 3][it * 16 + ty] = f2bf(v.w);
  }
  __syncthreads();
  #pragma unroll
  for (int it = 0; it < 4; ++it) {
    int d  = it * 16 + ty;
    int pb = tx * 4;
    ushort4 o;
    o.x = tile[d][pb + 0]; o.y = tile[d][pb + 1];
    o.z = tile[d][pb + 2]; o.w = tile[d][pb + 3];
    *(ushort4*)(Vt + ((size_t)h * HN + d0 + d) * S_GLOBAL + p0 + pb) = o;
  }
}

// ---- main attention kernel ----
// grid 1024, 256 threads (4 waves: qg x ks). Block = one head x 32 q-rows.
// Single 32KB LDS buffer (K 16K + V 16K), 2-phase per 64-key chunk:
//   issue gload_lds -> vmcnt(0) -> barrier -> compute -> barrier
// 4 blocks/CU resident; cross-block TLP hides the staging stall.
// K rows staged PERMUTED (A-pos a=sub*16+q holds key g(q)*8+sub*4+r(q)) so
// QK's D layout == PV's B layout: P stays in registers, no LDS roundtrip.
__global__ __launch_bounds__(256, 4)
void attn_kernel(const float* __restrict__ Q, const ushort* __restrict__ Kb,
                 const ushort* __restrict__ Vt, float* __restrict__ Out) {
  __shared__ ushort Klds[64 * 128];   // 16 KB (64 keys x 256B, row-swizzled)
  __shared__ ushort Vlds[128 * 64];   // 16 KB (128 d x 128B, row-swizzled)

  const int lane = threadIdx.x & 63;
  const int w    = threadIdx.x >> 6;     // 0..3
  const int qg   = w & 1;                // q-row group (16 rows)
  const int ks   = w >> 1;               // key-half 0/1
  const int qcol = lane & 15;
  const int g    = lane >> 4;

  const int bid  = blockIdx.x;
  const int kvh  = bid & 7;              // K/V head pinned to XCD L2
  const int j    = bid >> 3;             // 0..127
  const int head = 2 * kvh + (j & 1);
  const int slot = j >> 1;               // 0..63, light/heavy interleaved
  const int Tt   = (slot & 1) ? 32 + (slot >> 1) : (slot >> 1);  // 0..63
  const int tb   = Tt << 5;              // 32-row tile base
  const int tw   = tb + qg * 16;
  const int tq   = tw + qcol;

  // chunk list: light = [0 .. tb/64]; heavy = causal [16..] + anti [..63]
  int c0, nC, a0 = 0, n;
  if (tb < 1024) { c0 = 0; nC = (tb >> 6) + 1; n = nC; }
  else {
    c0 = 16; nC = ((tb + 31) >> 6) - 15;
    a0 = (tb + 2049) >> 6; n = nC + (64 - a0);
  }

  // Q fragments (B operand: col = q, k-slice = d)
  short8 qf[4];
  {
    const float* qb = Q + ((size_t)tq * NQ + head) * HN;
    #pragma unroll
    for (int ds = 0; ds < 4; ++ds) {
      const float4* p4 = (const float4*)(qb + ds * 32 + g * 8);
      float4 a = p4[0], b = p4[1];
      short8 f;
      f[0] = f2bf(a.x); f[1] = f2bf(a.y); f[2] = f2bf(a.z); f[3] = f2bf(a.w);
      f[4] = f2bf(b.x); f[5] = f2bf(b.y); f[6] = f2bf(b.z); f[7] = f2bf(b.w);
      qf[ds] = f;
    }
  }

  f32x4 acc[8];
  #pragma unroll
  for (int i = 0; i < 8; ++i) acc[i] = (f32x4){0.f, 0.f, 0.f, 0.f};
  float m_run = -1e30f, l_run = 0.f;

  const int rxv = (qcol & 7) << 4;       // V read-side swizzle term

  auto chunk_p0 = [&](int i) {
    return ((i < nC) ? (c0 + i) : (a0 + (i - nC))) << 6;
  };

  // stage one 64-key chunk into the single buffer (8 gload16 per lane-row set)
  auto stage = [&](int p0) {
    #pragma unroll
    for (int t = 0; t < 4; ++t) {
      int idx = (w * 4 + t) * 64 + lane;          // 0..1023
      int row = idx >> 4;                          // key row 0..63
      int cu  = (idx & 15) ^ (row & 7);            // swizzled 16B col unit
      gload16(Kb + ((size_t)(p0 + row) * NK + kvh) * HN + cu * 8,
              &Klds[(w * 4 + t) * 512]);
    }
    #pragma unroll
    for (int t = 0; t < 4; ++t) {
      int idx = (w * 4 + t) * 64 + lane;
      int d   = idx >> 3;                          // d row 0..127
      int pu  = (idx & 7) ^ (d & 7);               // swizzled 16B p unit
      gload16(Vt + ((size_t)kvh * HN + d) * S_GLOBAL + p0 + pu * 8,
              &Vlds[(w * 4 + t) * 512]);
    }
  };

  for (int c = 0; c < n; ++c) {
    stage(chunk_p0(c));
    asm volatile("s_waitcnt vmcnt(0)" ::: "memory");
    __syncthreads();

    const int p0   = chunk_p0(c);
    const bool anti = p0 >= 2048;
    const char* Klc = (const char*)Klds;
    const char* Vlc = (const char*)Vlds;

    const int p0s = p0 + ks * 32;   // this wave's 32-key half
    const bool activ = anti ? (p0s + 31 >= tw + 2049) : (p0s <= tw + 15);
    if (activ) {
      const bool needmask = anti ? (p0s < tw + 2064) : (p0s + 31 > tw);

      // K fragments, PERMUTED rows: A-pos (sub,qcol) <- key g(q)*8+sub*4+r(q)
      short8 kf[2][4];
      #pragma unroll
      for (int sub = 0; sub < 2; ++sub) {
        const int krow = ks * 32 + ((qcol >> 2) << 3) + sub * 4 + (qcol & 3);
        const int rbase = krow * 256;
        const int rxk = (krow & 7) << 4;
        #pragma unroll
        for (int ds = 0; ds < 4; ++ds)
          kf[sub][ds] = *(const short8*)(Klc + rbase + ((ds * 64 + g * 16) ^ rxk));
      }
      // V^T fragments (hoisted; ds latency overlaps QK MFMA)
      short8 vf[8];
      #pragma unroll
      for (int db = 0; db < 8; ++db)
        vf[db] = *(const short8*)(Vlc + (db * 16 + qcol) * 128 + ((ks * 64 + g * 16) ^ rxv));

      // S^T = K * Q^T ; lane(qcol,g) holds D rows m=g*4+r -> key g*8+sub*4+r
      f32x4 st[2];
      st[0] = (f32x4){0.f, 0.f, 0.f, 0.f};
      st[1] = (f32x4){0.f, 0.f, 0.f, 0.f};
      #pragma unroll
      for (int sub = 0; sub < 2; ++sub)
        #pragma unroll
        for (int ds = 0; ds < 4; ++ds)
          st[sub] = __builtin_amdgcn_mfma_f32_16x16x32_bf16(kf[sub][ds], qf[ds], st[sub], 0, 0, 0);

      float s_[8];
      #pragma unroll
      for (int sub = 0; sub < 2; ++sub) {
        #pragma unroll
        for (int r = 0; r < 4; ++r) {
          float sv = st[sub][r] * SCALE2;
          if (needmask) {
            int p = p0s + g * 8 + sub * 4 + r;     // permuted key index
            bool ok = anti ? (p >= tq + 2049) : (p <= tq);
            sv = ok ? sv : -INFINITY;
          }
          s_[sub * 4 + r] = sv;
        }
      }

      // online softmax (reduce over key axis: in-lane 8 + cross-g shfl)
      float mt = s_[0];
      #pragma unroll
      for (int i = 1; i < 8; ++i) mt = fmaxf(mt, s_[i]);
      mt = fmaxf(mt, __shfl_xor(mt, 16));
      mt = fmaxf(mt, __shfl_xor(mt, 32));
      float mnew = fmaxf(m_run, mt);
      float fsc  = __builtin_amdgcn_exp2f(m_run - mnew);
      float pv[8];
      float ps = 0.f;
      #pragma unroll
      for (int i = 0; i < 8; ++i) { pv[i] = __builtin_amdgcn_exp2f(s_[i] - mnew); ps += pv[i]; }
      ps += __shfl_xor(ps, 16);
      ps += __shfl_xor(ps, 32);
      l_run = l_run * fsc + ps;
      m_run = mnew;
      #pragma unroll
      for (int i = 0; i < 8; ++i) acc[i] *= fsc;

      // P stays in registers: pv[i] IS key g*8+i -> B-frag pack directly
      uint4 pu;
      pu.x = (unsigned)f2bf(pv[0]) | ((unsigned)f2bf(pv[1]) << 16);
      pu.y = (unsigned)f2bf(pv[2]) | ((unsigned)f2bf(pv[3]) << 16);
      pu.z = (unsigned)f2bf(pv[4]) | ((unsigned)f2bf(pv[5]) << 16);
      pu.w = (unsigned)f2bf(pv[6]) | ((unsigned)f2bf(pv[7]) << 16);
      short8 pf = __builtin_bit_cast(short8, pu);

      // O^T += V^T * P^T
      #pragma unroll
      for (int db = 0; db < 8; ++db)
        acc[db] = __builtin_amdgcn_mfma_f32_16x16x32_bf16(vf[db], pf, acc[db], 0, 0, 0);
    }
    __syncthreads();
  }

  // ---- 2-way key-half merge (ks=1 -> ks=0) through reused LDS ----
  float* mb  = (float*)&Klds[0];         // [2 qg][16 row][128 d] = 16 KB
  float* mlb = (float*)&Vlds[0];         // [2 qg][16 row][2]
  if (ks == 1) {
    if (g == 0) {
      mlb[(qg * 16 + qcol) * 2 + 0] = m_run;
      mlb[(qg * 16 + qcol) * 2 + 1] = l_run;
    }
    #pragma unroll
    for (int db = 0; db < 8; ++db)
      *(f32x4*)&mb[(qg * 16 + qcol) * 128 + db * 16 + g * 4] = acc[db];
  }
  __syncthreads();
  if (ks == 0) {
    float mr = mlb[(qg * 16 + qcol) * 2 + 0];
    float lr = mlb[(qg * 16 + qcol) * 2 + 1];
    float mnew = fmaxf(m_run, mr);
    float f0 = __builtin_amdgcn_exp2f(m_run - mnew);
    float fr = __builtin_amdgcn_exp2f(mr - mnew);
    float inv = 1.0f / (l_run * f0 + lr * fr);
    float* ob = Out + (size_t)tq * (NQ * HN) + head * HN + g * 4;
    #pragma unroll
    for (int db = 0; db < 8; ++db) {
      f32x4 o = *(const f32x4*)&mb[(qg * 16 + qcol) * 128 + db * 16 + g * 4];
      float4 r;
      r.x = (acc[db][0] * f0 + o[0] * fr) * inv;
      r.y = (acc[db][1] * f0 + o[1] * fr) * inv;
      r.z = (acc[db][2] * f0 + o[2] * fr) * inv;
      r.w = (acc[db][3] * f0 + o[3] * fr) * inv;
      *(float4*)(ob + db * 16) = r;
    }
  }
}

extern "C" void kernel_launch(void* const* d_in, const int* in_sizes, int n_in,
                              void* d_out, int out_size, void* d_ws, size_t ws_size,
                              hipStream_t stream) {
  const float* Q = (const float*)d_in[0];
  const float* K = (const float*)d_in[1];
  const float* V = (const float*)d_in[2];
  float* Out = (float*)d_out;

  ushort* Kb = (ushort*)d_ws;                         // 8 MB
  ushort* Vt = Kb + (size_t)S_GLOBAL * NK * HN;       // 8 MB

  k_convert<<<dim3((S_GLOBAL * NK * HN) / (256 * 4)), dim3(256), 0, stream>>>(K, Kb);
  v_transpose<<<dim3(NK * 2 * (S_GLOBAL / 64)), dim3(256), 0, stream>>>(V, Vt);
  attn_kernel<<<dim3(1024), dim3(256), 0, stream>>>(Q, Kb, Vt, Out);
}